// Round 10
// baseline (1464.447 us; speedup 1.0000x reference)
//
#include <hip/hip_runtime.h>

#define B_ 2048
#define L_ 32
#define H_ 512
#define H2 1024
#define H4 2048

typedef _Float16 half8 __attribute__((ext_vector_type(8)));
typedef _Float16 half4v __attribute__((ext_vector_type(4)));
typedef float f32x4 __attribute__((ext_vector_type(4)));

__device__ __forceinline__ float sigm(float x) { return 1.f / (1.f + __expf(-x)); }
__device__ __forceinline__ float tanh_f(float x) {
  float ax = fabsf(x);
  float e = __expf(2.f * ax);
  float t = 1.f - 2.f / (e + 1.f);
  return x < 0.f ? -t : t;
}
__device__ __forceinline__ float wave_sum(float v) {
#pragma unroll
  for (int o = 32; o; o >>= 1) v += __shfl_xor(v, o);
  return v;
}

__device__ __forceinline__ void gload_lds16(const _Float16* g, _Float16* l) {
  __builtin_amdgcn_global_load_lds((const __attribute__((address_space(1))) void*)g,
                                   (__attribute__((address_space(3))) void*)l, 16, 0, 0);
}

// counted-vmcnt waits (T4). vmcnt retires in issue order: waiting to N ensures
// all loads older than the N newest have landed. Cross-wave visibility of LDS
// staging still requires an s_barrier AFTER the wait (R9's bug: vmcnt is
// per-wave; barrier-before-stage left other waves' gload_lds un-ordered).
__device__ __forceinline__ void wait_vm12() { asm volatile("s_waitcnt vmcnt(12)" ::: "memory"); }
__device__ __forceinline__ void wait_vm8()  { asm volatile("s_waitcnt vmcnt(8)"  ::: "memory"); }
__device__ __forceinline__ void wait_vm0()  { asm volatile("s_waitcnt vmcnt(0)"  ::: "memory"); }

// ---------------- plain B^T GEMM: C[M,N] = A[M,K] @ Bmat[N,K]^T (fp16 in, f32 out)
// R8-proven structure: stage(next) -> wait -> barrier -> compute -> barrier.
__global__ __launch_bounds__(256, 2) void gemm_bt(
    const _Float16* __restrict__ A, int lda,
    const _Float16* __restrict__ Bmat, int ldb,
    float* __restrict__ C, int ldc, int K)
{
  __shared__ _Float16 As[2][128 * 64];
  __shared__ _Float16 Bs[2][128 * 64];
  const int tid = threadIdx.x;
  const int lane = tid & 63;
  const int w = tid >> 6;
  const int n0 = blockIdx.x * 128;
  const int m0 = blockIdx.y * 128;

  const int srow = lane >> 3;
  const int kcs = ((lane & 7) ^ srow) << 3;   // swizzled source offset (T2, rule #21)

  f32x4 acc[4][4] = {};
  const int wm = (w >> 1) * 64;
  const int wn = (w & 1) * 64;
  const int fr = lane & 15;

  const int nkt = K >> 6;
  auto stage = [&](int buf, int kt) {
    const int k0 = kt << 6;
#pragma unroll
    for (int i = 0; i < 4; ++i) {
      const int R0 = w * 32 + i * 8;
      gload_lds16(A + (size_t)(m0 + R0 + srow) * lda + (k0 + kcs), &As[buf][R0 * 64]);
      gload_lds16(Bmat + (size_t)(n0 + R0 + srow) * ldb + (k0 + kcs), &Bs[buf][R0 * 64]);
    }
  };
  auto compute = [&](int buf) {
    const char* Ab = (const char*)&As[buf][0];
    const char* Bb = (const char*)&Bs[buf][0];
#pragma unroll
    for (int kk = 0; kk < 2; ++kk) {
      const int so = (((kk << 2) + (lane >> 4)) ^ (fr & 7)) << 4;
      half8 af[4], bf[4];
#pragma unroll
      for (int m = 0; m < 4; ++m) af[m] = *(const half8*)(Ab + (wm + m * 16 + fr) * 128 + so);
#pragma unroll
      for (int n = 0; n < 4; ++n) bf[n] = *(const half8*)(Bb + (wn + n * 16 + fr) * 128 + so);
#pragma unroll
      for (int m = 0; m < 4; ++m)
#pragma unroll
        for (int n = 0; n < 4; ++n)
          acc[m][n] = __builtin_amdgcn_mfma_f32_16x16x32_f16(af[m], bf[n], acc[m][n], 0, 0, 0);
    }
  };

  stage(0, 0);
  int cur = 0;
  for (int kt = 0; kt < nkt; ++kt) {
    const bool pref = (kt + 1 < nkt);
    if (pref) { stage(cur ^ 1, kt + 1); wait_vm8(); }
    else      { wait_vm0(); }
    __builtin_amdgcn_s_barrier();    // current tile ready for ALL waves
    compute(cur);
    __builtin_amdgcn_s_barrier();    // all waves done reading before overwrite
    cur ^= 1;
  }

  const int r0 = (lane >> 4) * 4;
#pragma unroll
  for (int m = 0; m < 4; ++m)
#pragma unroll
    for (int n = 0; n < 4; ++n)
#pragma unroll
      for (int r = 0; r < 4; ++r) {
        const int row = m0 + wm + m * 16 + r0 + r;
        const int col = n0 + wn + n * 16 + fr;
        C[(size_t)row * ldc + col] = acc[m][n][r];
      }
}

// ---------------- fused LSTM step GEMM + pointwise update (per-step launch)
// A (x/h) via LDS (global_load_lds, swizzled source); B (weights) DIRECT to
// registers (8x global_load_dwordx4, static even/odd ping-pong, rule #20) --
// halves LDS-staging traffic and drops Bs (LDS 32KB).
// Barrier discipline = R8's proven order: stage(next)+loadB(next) -> wait_vm12
// -> s_barrier (cross-wave tile-ready) -> compute -> s_barrier (overwrite guard).
__global__ __launch_bounds__(256, 2) void gemm_lstm(
    const _Float16* __restrict__ Wpack,   // [2][2048][1024] gate-interleaved
    const float* __restrict__ bpack,      // [2][2048] interleaved
    const _Float16* __restrict__ chH,     // [B][L][512]
    _Float16* __restrict__ hstate,        // [2 parity][2 dir][B][512] (sorted pos)
    float* __restrict__ cstate,           // [2 dir][B][512] (sorted pos)
    _Float16* __restrict__ h_all,         // [B][L][1024] (original b)
    const int* __restrict__ perm,
    const int* __restrict__ lens_sorted,
    int step)
{
  const int lin = blockIdx.x;
  const int xcd = lin & 7;
  const int g8 = lin >> 3;                       // 0..63 within xcd
  const int dir = xcd >> 2;
  const int quad = xcd & 3;
  const int mt = ((g8 >> 3) << 1) + (quad >> 1); // striped: tiles die evenly per XCD
  const int nt = ((quad & 1) << 3) + (g8 & 7);
  const int m0 = mt * 128;
  const int n0 = nt * 128;
  if (lens_sorted[m0] <= step) return;           // dead tile

  __shared__ _Float16 As[2][128 * 64];
  const int tid = threadIdx.x;
  const int lane = tid & 63;
  const int w = tid >> 6;
  const int srow = lane >> 3;
  const int kcs = ((lane & 7) ^ srow) << 3;
  const int wm = (w >> 1) * 64;
  const int wn = (w & 1) * 64;
  const int fr = lane & 15;
  const int fk = (lane >> 4) * 8;

  // per-staged-row sources (fixed across k-tiles)
  const _Float16* xsrc[4];
  int posr[4];
#pragma unroll
  for (int i = 0; i < 4; ++i) {
    const int pos = m0 + w * 32 + i * 8 + srow;
    const int b = perm[pos];
    int idx;
    if (dir == 0) idx = step;
    else { const int t = lens_sorted[pos] - 1 - step; idx = t < 0 ? 0 : (t > 31 ? 31 : t); }
    xsrc[i] = chH + ((size_t)b * L_ + idx) * H_ + kcs;
    posr[i] = pos;
  }
  const _Float16* Wb = Wpack + (size_t)dir * H4 * H2;
  const _Float16* hprev = hstate + ((size_t)((step & 1) * 2 + dir)) * B_ * H_;
  _Float16* hnext = hstate + ((size_t)(((step + 1) & 1) * 2 + dir)) * B_ * H_;

  // B-fragment row pointers: this wave's W rows, k-base at fk.
  // Direct address reproduces the old swizzled-LDS fragment exactly (swizzle
  // cancels: LDS chunk p of row r held source chunk p^(r&7); read XOR undid it).
  const _Float16* wrow[4];
#pragma unroll
  for (int n = 0; n < 4; ++n)
    wrow[n] = Wb + (size_t)(n0 + wn + n * 16 + fr) * H2 + fk;

  f32x4 acc[4][4] = {};

  auto stageA = [&](int buf, int kt) {
    const int k0 = kt << 6;
#pragma unroll
    for (int i = 0; i < 4; ++i) {
      const int R0 = w * 32 + i * 8;
      const _Float16* sA = (k0 < 512) ? (xsrc[i] + k0)
                                      : (hprev + (size_t)posr[i] * H_ + (k0 - 512) + kcs);
      gload_lds16(sA, &As[buf][R0 * 64]);
    }
  };
  auto loadB = [&](half8 (&bf)[4][2], int kt) {
#pragma unroll
    for (int n = 0; n < 4; ++n)
#pragma unroll
      for (int kk = 0; kk < 2; ++kk)
        bf[n][kk] = *(const half8*)(wrow[n] + kt * 64 + kk * 32);
  };
  auto computeK = [&](int buf, half8 (&bf)[4][2]) {
    const char* Ab = (const char*)&As[buf][0];
#pragma unroll
    for (int kk = 0; kk < 2; ++kk) {
      const int so = (((kk << 2) + (lane >> 4)) ^ (fr & 7)) << 4;
      half8 af[4];
#pragma unroll
      for (int m = 0; m < 4; ++m) af[m] = *(const half8*)(Ab + (wm + m * 16 + fr) * 128 + so);
#pragma unroll
      for (int m = 0; m < 4; ++m)
#pragma unroll
        for (int n = 0; n < 4; ++n)
          acc[m][n] = __builtin_amdgcn_mfma_f32_16x16x32_f16(af[m], bf[n][kk], acc[m][n], 0, 0, 0);
    }
  };

  half8 bEven[4][2], bOdd[4][2];      // static ping-pong (rule #20)
  stageA(0, 0);
  loadB(bEven, 0);

#pragma unroll 1
  for (int kt = 0; kt < 16; kt += 2) {
    // ---- even slot: compute kt from (buf0, bEven); prefetch kt+1 into (buf1, bOdd)
    stageA(1, kt + 1);                 // buf1 overwrite guarded by prev odd slot's 2nd barrier
    loadB(bOdd, kt + 1);
    wait_vm12();                       // own 12 current-tile loads landed
    __builtin_amdgcn_s_barrier();      // ALL waves' tile-kt loads landed
    computeK(0, bEven);
    __builtin_amdgcn_s_barrier();      // all waves done reading buf0

    // ---- odd slot: compute kt+1 from (buf1, bOdd); prefetch kt+2 into (buf0, bEven)
    if (kt + 2 < 16) {
      stageA(0, kt + 2);
      loadB(bEven, kt + 2);
      wait_vm12();
    } else {
      wait_vm0();
    }
    __builtin_amdgcn_s_barrier();      // ALL waves' tile-(kt+1) loads landed
    computeK(1, bOdd);
    __builtin_amdgcn_s_barrier();      // all waves done reading buf1
  }

  // ---- fused LSTM epilogue: lane owns gates i,f,g,o (n=0..3) of hidden unit j
  const int r0 = (lane >> 4) * 4;
  const int j = ((n0 + wn) >> 6) * 16 + fr;
  const float bi = bpack[dir * H4 + n0 + wn + 0 * 16 + fr];
  const float bf_ = bpack[dir * H4 + n0 + wn + 1 * 16 + fr];
  const float bg = bpack[dir * H4 + n0 + wn + 2 * 16 + fr];
  const float bo = bpack[dir * H4 + n0 + wn + 3 * 16 + fr];
  float* cs = cstate + (size_t)dir * B_ * H_;

#pragma unroll
  for (int m = 0; m < 4; ++m)
#pragma unroll
    for (int r = 0; r < 4; ++r) {
      const int pos = m0 + wm + m * 16 + r0 + r;
      const float zi = acc[m][0][r] + bi;
      const float zf = acc[m][1][r] + bf_;
      const float zg = acc[m][2][r] + bg;
      const float zo = acc[m][3][r] + bo;
      const size_t ci = (size_t)pos * H_ + j;
      const float cn = sigm(zf) * cs[ci] + sigm(zi) * tanh_f(zg);
      const float h = sigm(zo) * tanh_f(cn);
      cs[ci] = cn;
      hnext[ci] = (_Float16)h;
      const int len = lens_sorted[pos];
      if (step < len) {
        const int b = perm[pos];
        const int t = (dir == 0) ? step : (len - 1 - step);
        h_all[((size_t)b * L_ + t) * H2 + dir * 512 + j] = (_Float16)h;
      }
    }
}

// ---------------- prep kernels
__global__ void cast_half_k(const float* __restrict__ s, _Float16* __restrict__ d, int n) {
  const int i = (blockIdx.x * 256 + threadIdx.x) * 4;
  if (i >= n) return;
  const float4 v = *(const float4*)(s + i);
  half4v h;
  h[0] = (_Float16)v.x; h[1] = (_Float16)v.y; h[2] = (_Float16)v.z; h[3] = (_Float16)v.w;
  *(half4v*)(d + i) = h;
}

__global__ void pack_wcat(const float* __restrict__ Wih_f, const float* __restrict__ Whh_f,
                          const float* __restrict__ Wih_b, const float* __restrict__ Whh_b,
                          _Float16* __restrict__ Wcat) {
  const int idx = blockIdx.x * 256 + threadIdx.x;   // 2*2048*512
  const int k = idx & 511;
  const int c = (idx >> 9) & 2047;
  const int dir = idx >> 20;
  const int g = (c >> 4) & 3;
  const int j = ((c >> 6) << 4) + (c & 15);
  const int n_orig = g * 512 + j;
  const float* Wih = dir ? Wih_b : Wih_f;
  const float* Whh = dir ? Whh_b : Whh_f;
  _Float16* row = Wcat + ((size_t)dir * H4 + c) * H2;
  row[k] = (_Float16)Wih[(size_t)n_orig * H_ + k];
  row[512 + k] = (_Float16)Whh[(size_t)n_orig * H_ + k];
}

__global__ void pack_bias(const float* __restrict__ bih_f, const float* __restrict__ bhh_f,
                          const float* __restrict__ bih_b, const float* __restrict__ bhh_b,
                          float* __restrict__ biascat) {
  const int idx = blockIdx.x * 256 + threadIdx.x;   // 2*2048
  const int dir = idx >> 11;
  const int c = idx & 2047;
  const int g = (c >> 4) & 3;
  const int j = ((c >> 6) << 4) + (c & 15);
  const int n = g * 512 + j;
  biascat[idx] = dir ? (bih_b[n] + bhh_b[n]) : (bih_f[n] + bhh_f[n]);
}

__global__ void transpose_v(const float* __restrict__ V, _Float16* __restrict__ Vt) {
  const int idx = blockIdx.x * 256 + threadIdx.x;   // 1024*1024
  const int d = idx >> 10;
  const int e = idx & 1023;
  Vt[(size_t)e * H2 + d] = (_Float16)V[idx];
}

__global__ void build_rhs(const float* __restrict__ nt_emb, const int* __restrict__ nt_id,
                          const float* __restrict__ stack_state, _Float16* __restrict__ rhs_h) {
  const int idx = blockIdx.x * 256 + threadIdx.x;   // 2048*1024
  const int b = idx >> 10;
  const int d = idx & 1023;
  const float v = (d < 512) ? nt_emb[(size_t)nt_id[b] * H_ + d]
                            : stack_state[(size_t)b * H_ + (d - 512)];
  rhs_h[idx] = (_Float16)v;
}

// ---------------- length sort (descending) for tile-skip
__global__ void sort1_k(const int* __restrict__ lens, int* __restrict__ offs, int* __restrict__ cursor) {
  __shared__ int cnt[33];
  const int tid = threadIdx.x;
  if (tid < 33) cnt[tid] = 0;
  __syncthreads();
  for (int i = tid; i < B_; i += 256) atomicAdd(&cnt[lens[i]], 1);
  __syncthreads();
  if (tid == 0) {
    int acc = 0;
    for (int l = 32; l >= 1; --l) { offs[l] = acc; acc += cnt[l]; }
  }
  if (tid < 33) cursor[tid] = 0;
}

__global__ void sort2_k(const int* __restrict__ lens, const int* __restrict__ offs,
                        int* __restrict__ cursor, int* __restrict__ perm,
                        int* __restrict__ lens_sorted) {
  const int b = blockIdx.x * 256 + threadIdx.x;
  const int len = lens[b];
  const int pos = offs[len] + atomicAdd(&cursor[len], 1);
  perm[pos] = b;
  lens_sorted[pos] = len;
}

__global__ void marker_k(float* out) { out[threadIdx.x] = 12345.0f; }

// ---------------- attention: logits -> softmax -> weighted sum -> LN
__global__ __launch_bounds__(256) void attn_kernel(
    const _Float16* __restrict__ h_all, const float* __restrict__ u,
    const int* __restrict__ lens,
    const float* __restrict__ g2, const float* __restrict__ b2,
    float* __restrict__ attn_out, float* __restrict__ wc_f, _Float16* __restrict__ gin_h) {
  __shared__ float u_s[H2];
  __shared__ float logit_s[L_];
  __shared__ float attn_s[L_];
  __shared__ float red_s[8];
  const int b = blockIdx.x;
  const int tid = threadIdx.x;
  const int lane = tid & 63;
  const int w = tid >> 6;
#pragma unroll
  for (int r = 0; r < 4; ++r) u_s[tid + r * 256] = u[(size_t)b * H2 + tid + r * 256];
  __syncthreads();
  const _Float16* hb = h_all + (size_t)b * L_ * H2;
  const int len = lens[b];
#pragma unroll
  for (int li = 0; li < 8; ++li) {
    const int l = w * 8 + li;
    float p = 0.f;
    if (l < len) {
      const _Float16* hr = hb + (size_t)l * H2;
#pragma unroll
      for (int j = 0; j < 16; ++j) {
        const int e = lane + 64 * j;
        p += (float)hr[e] * u_s[e];
      }
      p = wave_sum(p);
    }
    if (lane == 0) logit_s[l] = p;
  }
  __syncthreads();
  if (w == 0) {
    const int l = lane;
    float v = (l < len) ? logit_s[l] : -1e30f;
    float m = v;
#pragma unroll
    for (int o = 32; o; o >>= 1) m = fmaxf(m, __shfl_xor(m, o));
    const float e = (l < len) ? __expf(v - m) : 0.f;
    float s = e;
#pragma unroll
    for (int o = 32; o; o >>= 1) s += __shfl_xor(s, o);
    const float a = e / s;
    if (l < L_) { attn_s[l] = a; attn_out[(size_t)b * L_ + l] = a; }
  }
  __syncthreads();
  float wcv[4] = {0.f, 0.f, 0.f, 0.f};
  for (int l = 0; l < len; ++l) {
    const float a = attn_s[l];
    const _Float16* hr = hb + (size_t)l * H2;
#pragma unroll
    for (int r = 0; r < 4; ++r) wcv[r] += a * (float)hr[tid + r * 256];
  }
  float s1 = wcv[0] + wcv[1] + wcv[2] + wcv[3];
  float s2 = wcv[0] * wcv[0] + wcv[1] * wcv[1] + wcv[2] * wcv[2] + wcv[3] * wcv[3];
  s1 = wave_sum(s1);
  s2 = wave_sum(s2);
  if (lane == 0) { red_s[w] = s1; red_s[4 + w] = s2; }
  __syncthreads();
  const float S1 = red_s[0] + red_s[1] + red_s[2] + red_s[3];
  const float S2 = red_s[4] + red_s[5] + red_s[6] + red_s[7];
  const float mu = S1 * (1.f / H2);
  const float var = S2 * (1.f / H2) - mu * mu;
  const float rstd = rsqrtf(var + 1e-5f);
#pragma unroll
  for (int r = 0; r < 4; ++r) {
    const int e = tid + r * 256;
    const float y = (wcv[r] - mu) * rstd * g2[e] + b2[e];
    wc_f[(size_t)b * H2 + e] = y;
    gin_h[(size_t)b * H4 + H2 + e] = (_Float16)y;
  }
}

// ---------------- LN(nt_emb2[nt_id])
__global__ __launch_bounds__(256) void nt2_kernel(
    const float* __restrict__ nt_emb2, const int* __restrict__ nt_id,
    const float* __restrict__ g1, const float* __restrict__ b1,
    float* __restrict__ nt2_f, _Float16* __restrict__ gin_h) {
  __shared__ float red_s[8];
  const int b = blockIdx.x;
  const int tid = threadIdx.x;
  const int lane = tid & 63;
  const int w = tid >> 6;
  const float* x = nt_emb2 + (size_t)nt_id[b] * H2;
  float v[4];
  float s1 = 0.f, s2 = 0.f;
#pragma unroll
  for (int r = 0; r < 4; ++r) {
    v[r] = x[tid + r * 256];
    s1 += v[r];
    s2 += v[r] * v[r];
  }
  s1 = wave_sum(s1);
  s2 = wave_sum(s2);
  if (lane == 0) { red_s[w] = s1; red_s[4 + w] = s2; }
  __syncthreads();
  const float S1 = red_s[0] + red_s[1] + red_s[2] + red_s[3];
  const float S2 = red_s[4] + red_s[5] + red_s[6] + red_s[7];
  const float mu = S1 * (1.f / H2);
  const float var = S2 * (1.f / H2) - mu * mu;
  const float rstd = rsqrtf(var + 1e-5f);
#pragma unroll
  for (int r = 0; r < 4; ++r) {
    const int e = tid + r * 256;
    const float y = (v[r] - mu) * rstd * g1[e] + b1[e];
    nt2_f[(size_t)b * H2 + e] = y;
    gin_h[(size_t)b * H4 + e] = (_Float16)y;
  }
}

__global__ void gate_epi(const float* __restrict__ gpre, const float* __restrict__ gate_b,
                         const float* __restrict__ nt2_f, const float* __restrict__ wc_f,
                         float* __restrict__ g_out, _Float16* __restrict__ cmix_h) {
  const int idx = blockIdx.x * 256 + threadIdx.x;  // < B*H2
  const int j = idx & (H2 - 1);
  const float g = sigm(gpre[idx] + gate_b[j]);
  g_out[idx] = g;
  const float c = g * nt2_f[idx] + (1.f - g) * wc_f[idx];
  cmix_h[idx] = (_Float16)c;
}

__global__ void out_epi(const float* __restrict__ opre, const float* __restrict__ out_b,
                        float* __restrict__ outp) {
  const int idx = blockIdx.x * 256 + threadIdx.x;  // < B*H
  const int j = idx & (H_ - 1);
  const float v = opre[idx] + out_b[j];
  outp[idx] = v > 0.f ? v : 0.f;
}

extern "C" void kernel_launch(void* const* d_in, const int* in_sizes, int n_in,
                              void* d_out, int out_size, void* d_ws, size_t ws_size,
                              hipStream_t stream) {
  const float* children = (const float*)d_in[0];
  const int* lens = (const int*)d_in[1];
  const int* nt_id = (const int*)d_in[3];
  const float* stack_state = (const float*)d_in[4];
  const float* Wih_f = (const float*)d_in[5];
  const float* Whh_f = (const float*)d_in[6];
  const float* bih_f = (const float*)d_in[7];
  const float* bhh_f = (const float*)d_in[8];
  const float* Wih_b = (const float*)d_in[9];
  const float* Whh_b = (const float*)d_in[10];
  const float* bih_b = (const float*)d_in[11];
  const float* bhh_b = (const float*)d_in[12];
  const float* V = (const float*)d_in[13];
  const float* nt_emb = (const float*)d_in[14];
  const float* nt_emb2 = (const float*)d_in[15];
  const float* ln1_g = (const float*)d_in[16];
  const float* ln1_b = (const float*)d_in[17];
  const float* ln2_g = (const float*)d_in[18];
  const float* ln2_b = (const float*)d_in[19];
  const float* gate_W = (const float*)d_in[20];
  const float* gate_b = (const float*)d_in[21];
  const float* out_W = (const float*)d_in[22];
  const float* out_b = (const float*)d_in[23];

  float* out = (float*)d_out;
  float* attn_out = out + (size_t)B_ * H_;
  float* g_out = attn_out + (size_t)B_ * L_;

  char* wsp = (char*)d_ws;
  size_t off = 0;
  auto alloc = [&](size_t bytes) {
    char* p = wsp + off;
    off += (bytes + 255) & ~(size_t)255;
    return p;
  };
  _Float16* ch_h = (_Float16*)alloc((size_t)B_ * L_ * H_ * 2);
  _Float16* h_all = (_Float16*)alloc((size_t)B_ * L_ * H2 * 2);
  _Float16* Wcat = (_Float16*)alloc((size_t)2 * H4 * H2 * 2);
  float* biascat = (float*)alloc((size_t)2 * H4 * 4);
  _Float16* Vt = (_Float16*)alloc((size_t)H2 * H2 * 2);
  _Float16* gateWh = (_Float16*)alloc((size_t)H2 * H4 * 2);
  _Float16* outWh = (_Float16*)alloc((size_t)H_ * H2 * 2);
  _Float16* rhs_h = (_Float16*)alloc((size_t)B_ * H2 * 2);
  float* u_f = (float*)alloc((size_t)B_ * H2 * 4);
  _Float16* hstate = (_Float16*)alloc((size_t)2 * 2 * B_ * H_ * 2);  // [parity][dir][B][H]
  float* cstate = (float*)alloc((size_t)2 * B_ * H_ * 4);
  float* wc_f = (float*)alloc((size_t)B_ * H2 * 4);
  float* nt2_f = (float*)alloc((size_t)B_ * H2 * 4);
  _Float16* gin_h = (_Float16*)alloc((size_t)B_ * H4 * 2);
  float* gpre_f = (float*)alloc((size_t)B_ * H2 * 4);
  _Float16* cmix_h = (_Float16*)alloc((size_t)B_ * H2 * 2);
  float* opre_f = (float*)alloc((size_t)B_ * H_ * 4);
  int* sort_offs = (int*)alloc(64 * 4);
  int* sort_cursor = (int*)alloc(64 * 4);
  int* perm = (int*)alloc((size_t)B_ * 4);
  int* lens_sorted = (int*)alloc((size_t)B_ * 4);

  if (off > ws_size) {
    marker_k<<<1, 64, 0, stream>>>(out);
    return;
  }

  // ---- prep
  cast_half_k<<<32768, 256, 0, stream>>>(children, ch_h, B_ * L_ * H_);
  cast_half_k<<<2048, 256, 0, stream>>>(gate_W, gateWh, H2 * H4);
  cast_half_k<<<512, 256, 0, stream>>>(out_W, outWh, H_ * H2);
  pack_wcat<<<8192, 256, 0, stream>>>(Wih_f, Whh_f, Wih_b, Whh_b, Wcat);
  pack_bias<<<16, 256, 0, stream>>>(bih_f, bhh_f, bih_b, bhh_b, biascat);
  transpose_v<<<4096, 256, 0, stream>>>(V, Vt);
  build_rhs<<<8192, 256, 0, stream>>>(nt_emb, nt_id, stack_state, rhs_h);
  hipMemsetAsync(hstate, 0, (size_t)2 * 2 * B_ * H_ * 2, stream);
  hipMemsetAsync(cstate, 0, (size_t)2 * B_ * H_ * 4, stream);
  sort1_k<<<1, 256, 0, stream>>>(lens, sort_offs, sort_cursor);
  sort2_k<<<8, 256, 0, stream>>>(lens, sort_offs, sort_cursor, perm, lens_sorted);
  nt2_kernel<<<2048, 256, 0, stream>>>(nt_emb2, nt_id, ln1_g, ln1_b, nt2_f, gin_h);

  // ---- u = rhs @ V
  gemm_bt<<<dim3(8, 16, 1), 256, 0, stream>>>(rhs_h, H2, Vt, H2, u_f, H2, H2);

  // ---- bidirectional LSTM, 32 per-step launches (B-direct-reg pipeline inside)
  for (int t = 0; t < 32; ++t) {
    gemm_lstm<<<512, 256, 0, stream>>>(
        Wcat, biascat, ch_h, hstate, cstate, h_all, perm, lens_sorted, t);
  }

  // ---- attention + LN2
  attn_kernel<<<2048, 256, 0, stream>>>(h_all, u_f, lens, ln2_g, ln2_b, attn_out, wc_f, gin_h);

  // ---- gate MLP
  gemm_bt<<<dim3(8, 16, 1), 256, 0, stream>>>(gin_h, H4, gateWh, H4, gpre_f, H2, H4);
  gate_epi<<<8192, 256, 0, stream>>>(gpre_f, gate_b, nt2_f, wc_f, g_out, cmix_h);

  // ---- output projection
  gemm_bt<<<dim3(4, 16, 1), 256, 0, stream>>>(cmix_h, H2, outWh, H2, opre_f, H_, H2);
  out_epi<<<4096, 256, 0, stream>>>(opre_f, out_b, out);
}

// Round 11
// 1079.602 us; speedup vs baseline: 1.3565x; 1.3565x over previous
//
#include <hip/hip_runtime.h>

#define B_ 2048
#define L_ 32
#define H_ 512
#define H2 1024
#define H4 2048

typedef _Float16 half8 __attribute__((ext_vector_type(8)));
typedef _Float16 half4v __attribute__((ext_vector_type(4)));
typedef float f32x4 __attribute__((ext_vector_type(4)));

__device__ __forceinline__ float sigm(float x) { return 1.f / (1.f + __expf(-x)); }
__device__ __forceinline__ float tanh_f(float x) {
  float ax = fabsf(x);
  float e = __expf(2.f * ax);
  float t = 1.f - 2.f / (e + 1.f);
  return x < 0.f ? -t : t;
}
__device__ __forceinline__ float wave_sum(float v) {
#pragma unroll
  for (int o = 32; o; o >>= 1) v += __shfl_xor(v, o);
  return v;
}

__device__ __forceinline__ void gload_lds16(const _Float16* g, _Float16* l) {
  __builtin_amdgcn_global_load_lds((const __attribute__((address_space(1))) void*)g,
                                   (__attribute__((address_space(3))) void*)l, 16, 0, 0);
}

// counted-vmcnt waits (T4): prefetched tile's loads stay in flight across the
// barrier; wait only for the current tile. Barrier AFTER the wait gives
// cross-wave visibility (vmcnt is per-wave -- R9's lesson).
__device__ __forceinline__ void wait_vm8() { asm volatile("s_waitcnt vmcnt(8)" ::: "memory"); }
__device__ __forceinline__ void wait_vm0() { asm volatile("s_waitcnt vmcnt(0)" ::: "memory"); }

// ---------------- B^T GEMM: C[M,N] = A[M,K] @ Bmat[N,K]^T (fp16 in, f32 out)
// R8-proven pipeline: stage(next) -> wait_vm8 -> barrier -> compute -> barrier.
// EPI 0: plain C store. EPI 1: gate (sigmoid+mix -> g_out + fp16 cmix).
// EPI 2: bias+ReLU -> out.
template <int EPI>
__global__ __launch_bounds__(256, 2) void gemm_bt(
    const _Float16* __restrict__ A, int lda,
    const _Float16* __restrict__ Bmat, int ldb,
    float* __restrict__ C, int ldc, int K,
    const float* __restrict__ bias,
    const float* __restrict__ aux1,   // EPI1: nt2_f
    const float* __restrict__ aux2,   // EPI1: wc_f
    _Float16* __restrict__ hout)      // EPI1: cmix_h
{
  __shared__ _Float16 As[2][128 * 64];
  __shared__ _Float16 Bs[2][128 * 64];
  const int tid = threadIdx.x;
  const int lane = tid & 63;
  const int w = tid >> 6;
  const int n0 = blockIdx.x * 128;
  const int m0 = blockIdx.y * 128;

  const int srow = lane >> 3;
  const int kcs = ((lane & 7) ^ srow) << 3;   // swizzled source offset (T2, rule #21)

  f32x4 acc[4][4] = {};
  const int wm = (w >> 1) * 64;
  const int wn = (w & 1) * 64;
  const int fr = lane & 15;

  const int nkt = K >> 6;
  auto stage = [&](int buf, int kt) {
    const int k0 = kt << 6;
#pragma unroll
    for (int i = 0; i < 4; ++i) {
      const int R0 = w * 32 + i * 8;
      gload_lds16(A + (size_t)(m0 + R0 + srow) * lda + (k0 + kcs), &As[buf][R0 * 64]);
      gload_lds16(Bmat + (size_t)(n0 + R0 + srow) * ldb + (k0 + kcs), &Bs[buf][R0 * 64]);
    }
  };
  auto compute = [&](int buf) {
    const char* Ab = (const char*)&As[buf][0];
    const char* Bb = (const char*)&Bs[buf][0];
#pragma unroll
    for (int kk = 0; kk < 2; ++kk) {
      const int so = (((kk << 2) + (lane >> 4)) ^ (fr & 7)) << 4;
      half8 af[4], bf[4];
#pragma unroll
      for (int m = 0; m < 4; ++m) af[m] = *(const half8*)(Ab + (wm + m * 16 + fr) * 128 + so);
#pragma unroll
      for (int n = 0; n < 4; ++n) bf[n] = *(const half8*)(Bb + (wn + n * 16 + fr) * 128 + so);
#pragma unroll
      for (int m = 0; m < 4; ++m)
#pragma unroll
        for (int n = 0; n < 4; ++n)
          acc[m][n] = __builtin_amdgcn_mfma_f32_16x16x32_f16(af[m], bf[n], acc[m][n], 0, 0, 0);
    }
  };

  stage(0, 0);
  int cur = 0;
  for (int kt = 0; kt < nkt; ++kt) {
    const bool pref = (kt + 1 < nkt);
    if (pref) { stage(cur ^ 1, kt + 1); wait_vm8(); }
    else      { wait_vm0(); }
    __builtin_amdgcn_s_barrier();    // current tile ready for ALL waves
    compute(cur);
    __builtin_amdgcn_s_barrier();    // all waves done reading before overwrite
    cur ^= 1;
  }

  const int r0 = (lane >> 4) * 4;
#pragma unroll
  for (int m = 0; m < 4; ++m)
#pragma unroll
    for (int n = 0; n < 4; ++n)
#pragma unroll
      for (int r = 0; r < 4; ++r) {
        const int row = m0 + wm + m * 16 + r0 + r;
        const int col = n0 + wn + n * 16 + fr;
        const float a = acc[m][n][r];
        if constexpr (EPI == 0) {
          C[(size_t)row * ldc + col] = a;
        } else if constexpr (EPI == 1) {
          const float g = sigm(a + bias[col]);
          const size_t ix = (size_t)row * H2 + col;
          C[ix] = g;                                   // g_out
          const float c = g * aux1[ix] + (1.f - g) * aux2[ix];
          hout[ix] = (_Float16)c;                      // cmix fp16
        } else {
          const float v = a + bias[col];
          C[(size_t)row * ldc + col] = v > 0.f ? v : 0.f;
        }
      }
}

// ---------------- fused LSTM step GEMM + pointwise update (R8 structure, proven)
__global__ __launch_bounds__(256, 2) void gemm_lstm(
    const _Float16* __restrict__ Wpack,   // [2][2048][1024] gate-interleaved
    const float* __restrict__ bpack,      // [2][2048] interleaved
    const _Float16* __restrict__ chH,     // [B][L][512]
    _Float16* __restrict__ hstate,        // [2 parity][2 dir][B][512] (sorted pos)
    float* __restrict__ cstate,           // [2 dir][B][512] (sorted pos)
    _Float16* __restrict__ h_all,         // [B][L][1024] (original b)
    const int* __restrict__ perm,
    const int* __restrict__ lens_sorted,
    int step)
{
  const int lin = blockIdx.x;
  const int xcd = lin & 7;
  const int g8 = lin >> 3;                       // 0..63 within xcd
  const int dir = xcd >> 2;
  const int quad = xcd & 3;
  const int mt = ((g8 >> 3) << 1) + (quad >> 1); // striped: tiles die evenly per XCD
  const int nt = ((quad & 1) << 3) + (g8 & 7);
  const int m0 = mt * 128;
  const int n0 = nt * 128;
  if (lens_sorted[m0] <= step) return;           // dead tile

  __shared__ _Float16 As[2][128 * 64];
  __shared__ _Float16 Bs[2][128 * 64];
  const int tid = threadIdx.x;
  const int lane = tid & 63;
  const int w = tid >> 6;
  const int srow = lane >> 3;
  const int kcs = ((lane & 7) ^ srow) << 3;
  const int wm = (w >> 1) * 64;
  const int wn = (w & 1) * 64;
  const int fr = lane & 15;

  // per-staged-row sources (fixed across k-tiles)
  const _Float16* xsrc[4];
  int posr[4];
#pragma unroll
  for (int i = 0; i < 4; ++i) {
    const int pos = m0 + w * 32 + i * 8 + srow;
    const int b = perm[pos];
    int idx;
    if (dir == 0) idx = step;
    else { const int t = lens_sorted[pos] - 1 - step; idx = t < 0 ? 0 : (t > 31 ? 31 : t); }
    xsrc[i] = chH + ((size_t)b * L_ + idx) * H_ + kcs;
    posr[i] = pos;
  }
  const _Float16* Wb = Wpack + (size_t)dir * H4 * H2;
  const _Float16* hprev = hstate + ((size_t)((step & 1) * 2 + dir)) * B_ * H_;
  _Float16* hnext = hstate + ((size_t)(((step + 1) & 1) * 2 + dir)) * B_ * H_;

  f32x4 acc[4][4] = {};

  auto stage = [&](int buf, int kt) {
    const int k0 = kt << 6;
#pragma unroll
    for (int i = 0; i < 4; ++i) {
      const int R0 = w * 32 + i * 8;
      const _Float16* sA = (k0 < 512) ? (xsrc[i] + k0)
                                      : (hprev + (size_t)posr[i] * H_ + (k0 - 512) + kcs);
      gload_lds16(sA, &As[buf][R0 * 64]);
      gload_lds16(Wb + (size_t)(n0 + R0 + srow) * H2 + k0 + kcs, &Bs[buf][R0 * 64]);
    }
  };
  auto compute = [&](int buf) {
    const char* Ab = (const char*)&As[buf][0];
    const char* Bb = (const char*)&Bs[buf][0];
#pragma unroll
    for (int kk = 0; kk < 2; ++kk) {
      const int so = (((kk << 2) + (lane >> 4)) ^ (fr & 7)) << 4;
      half8 af[4], bf[4];
#pragma unroll
      for (int m = 0; m < 4; ++m) af[m] = *(const half8*)(Ab + (wm + m * 16 + fr) * 128 + so);
#pragma unroll
      for (int n = 0; n < 4; ++n) bf[n] = *(const half8*)(Bb + (wn + n * 16 + fr) * 128 + so);
#pragma unroll
      for (int m = 0; m < 4; ++m)
#pragma unroll
        for (int n = 0; n < 4; ++n)
          acc[m][n] = __builtin_amdgcn_mfma_f32_16x16x32_f16(af[m], bf[n], acc[m][n], 0, 0, 0);
    }
  };

  stage(0, 0);
  int cur = 0;
  for (int kt = 0; kt < 16; ++kt) {
    const bool pref = (kt + 1 < 16);
    if (pref) { stage(cur ^ 1, kt + 1); wait_vm8(); }
    else      { wait_vm0(); }
    __builtin_amdgcn_s_barrier();
    compute(cur);
    __builtin_amdgcn_s_barrier();
    cur ^= 1;
  }

  // ---- fused LSTM epilogue: lane owns gates i,f,g,o (n=0..3) of hidden unit j
  const int r0 = (lane >> 4) * 4;
  const int j = ((n0 + wn) >> 6) * 16 + fr;
  const float bi = bpack[dir * H4 + n0 + wn + 0 * 16 + fr];
  const float bf_ = bpack[dir * H4 + n0 + wn + 1 * 16 + fr];
  const float bg = bpack[dir * H4 + n0 + wn + 2 * 16 + fr];
  const float bo = bpack[dir * H4 + n0 + wn + 3 * 16 + fr];
  float* cs = cstate + (size_t)dir * B_ * H_;

#pragma unroll
  for (int m = 0; m < 4; ++m)
#pragma unroll
    for (int r = 0; r < 4; ++r) {
      const int pos = m0 + wm + m * 16 + r0 + r;
      const float zi = acc[m][0][r] + bi;
      const float zf = acc[m][1][r] + bf_;
      const float zg = acc[m][2][r] + bg;
      const float zo = acc[m][3][r] + bo;
      const size_t ci = (size_t)pos * H_ + j;
      const float cn = sigm(zf) * cs[ci] + sigm(zi) * tanh_f(zg);
      const float h = sigm(zo) * tanh_f(cn);
      cs[ci] = cn;
      hnext[ci] = (_Float16)h;
      const int len = lens_sorted[pos];
      if (step < len) {
        const int b = perm[pos];
        const int t = (dir == 0) ? step : (len - 1 - step);
        h_all[((size_t)b * L_ + t) * H2 + dir * 512 + j] = (_Float16)h;
      }
    }
}

// ---------------- prep kernels
__global__ void cast_half_k(const float* __restrict__ s, _Float16* __restrict__ d, int n) {
  const int i = (blockIdx.x * 256 + threadIdx.x) * 4;
  if (i >= n) return;
  const float4 v = *(const float4*)(s + i);
  half4v h;
  h[0] = (_Float16)v.x; h[1] = (_Float16)v.y; h[2] = (_Float16)v.z; h[3] = (_Float16)v.w;
  *(half4v*)(d + i) = h;
}

__global__ void pack_wcat(const float* __restrict__ Wih_f, const float* __restrict__ Whh_f,
                          const float* __restrict__ Wih_b, const float* __restrict__ Whh_b,
                          _Float16* __restrict__ Wcat) {
  const int idx = blockIdx.x * 256 + threadIdx.x;   // 2*2048*512
  const int k = idx & 511;
  const int c = (idx >> 9) & 2047;
  const int dir = idx >> 20;
  const int g = (c >> 4) & 3;
  const int j = ((c >> 6) << 4) + (c & 15);
  const int n_orig = g * 512 + j;
  const float* Wih = dir ? Wih_b : Wih_f;
  const float* Whh = dir ? Whh_b : Whh_f;
  _Float16* row = Wcat + ((size_t)dir * H4 + c) * H2;
  row[k] = (_Float16)Wih[(size_t)n_orig * H_ + k];
  row[512 + k] = (_Float16)Whh[(size_t)n_orig * H_ + k];
}

// merged: build_rhs (all 2M) + transpose_v (first 1M) + pack_bias (first 4096)
__global__ void prep_misc(const float* __restrict__ nt_emb, const int* __restrict__ nt_id,
                          const float* __restrict__ stack_state, _Float16* __restrict__ rhs_h,
                          const float* __restrict__ V, _Float16* __restrict__ Vt,
                          const float* __restrict__ bih_f, const float* __restrict__ bhh_f,
                          const float* __restrict__ bih_b, const float* __restrict__ bhh_b,
                          float* __restrict__ biascat) {
  const int idx = blockIdx.x * 256 + threadIdx.x;   // 2048*1024
  const int b = idx >> 10;
  const int d = idx & 1023;
  const float v = (d < 512) ? nt_emb[(size_t)nt_id[b] * H_ + d]
                            : stack_state[(size_t)b * H_ + (d - 512)];
  rhs_h[idx] = (_Float16)v;
  if (idx < (1 << 20)) {
    const int dd = idx >> 10;
    const int e = idx & 1023;
    Vt[(size_t)e * H2 + dd] = (_Float16)V[idx];
  }
  if (idx < 4096) {
    const int dir = idx >> 11;
    const int c = idx & 2047;
    const int g = (c >> 4) & 3;
    const int j = ((c >> 6) << 4) + (c & 15);
    const int n = g * 512 + j;
    biascat[idx] = dir ? (bih_b[n] + bhh_b[n]) : (bih_f[n] + bhh_f[n]);
  }
}

// ---------------- length sort (descending) for tile-skip
__global__ void sort1_k(const int* __restrict__ lens, int* __restrict__ offs, int* __restrict__ cursor) {
  __shared__ int cnt[33];
  const int tid = threadIdx.x;
  if (tid < 33) cnt[tid] = 0;
  __syncthreads();
  for (int i = tid; i < B_; i += 256) atomicAdd(&cnt[lens[i]], 1);
  __syncthreads();
  if (tid == 0) {
    int acc = 0;
    for (int l = 32; l >= 1; --l) { offs[l] = acc; acc += cnt[l]; }
  }
  if (tid < 33) cursor[tid] = 0;
}

__global__ void sort2_k(const int* __restrict__ lens, const int* __restrict__ offs,
                        int* __restrict__ cursor, int* __restrict__ perm,
                        int* __restrict__ lens_sorted) {
  const int b = blockIdx.x * 256 + threadIdx.x;
  const int len = lens[b];
  const int pos = offs[len] + atomicAdd(&cursor[len], 1);
  perm[pos] = b;
  lens_sorted[pos] = len;
}

__global__ void marker_k(float* out) { out[threadIdx.x] = 12345.0f; }

// ---------------- attention: logits -> softmax -> weighted sum -> LN
__global__ __launch_bounds__(256) void attn_kernel(
    const _Float16* __restrict__ h_all, const float* __restrict__ u,
    const int* __restrict__ lens,
    const float* __restrict__ g2, const float* __restrict__ b2,
    float* __restrict__ attn_out, float* __restrict__ wc_f, _Float16* __restrict__ gin_h) {
  __shared__ float u_s[H2];
  __shared__ float logit_s[L_];
  __shared__ float attn_s[L_];
  __shared__ float red_s[8];
  const int b = blockIdx.x;
  const int tid = threadIdx.x;
  const int lane = tid & 63;
  const int w = tid >> 6;
#pragma unroll
  for (int r = 0; r < 4; ++r) u_s[tid + r * 256] = u[(size_t)b * H2 + tid + r * 256];
  __syncthreads();
  const _Float16* hb = h_all + (size_t)b * L_ * H2;
  const int len = lens[b];
#pragma unroll
  for (int li = 0; li < 8; ++li) {
    const int l = w * 8 + li;
    float p = 0.f;
    if (l < len) {
      const _Float16* hr = hb + (size_t)l * H2;
#pragma unroll
      for (int j = 0; j < 16; ++j) {
        const int e = lane + 64 * j;
        p += (float)hr[e] * u_s[e];
      }
      p = wave_sum(p);
    }
    if (lane == 0) logit_s[l] = p;
  }
  __syncthreads();
  if (w == 0) {
    const int l = lane;
    float v = (l < len) ? logit_s[l] : -1e30f;
    float m = v;
#pragma unroll
    for (int o = 32; o; o >>= 1) m = fmaxf(m, __shfl_xor(m, o));
    const float e = (l < len) ? __expf(v - m) : 0.f;
    float s = e;
#pragma unroll
    for (int o = 32; o; o >>= 1) s += __shfl_xor(s, o);
    const float a = e / s;
    if (l < L_) { attn_s[l] = a; attn_out[(size_t)b * L_ + l] = a; }
  }
  __syncthreads();
  float wcv[4] = {0.f, 0.f, 0.f, 0.f};
  for (int l = 0; l < len; ++l) {
    const float a = attn_s[l];
    const _Float16* hr = hb + (size_t)l * H2;
#pragma unroll
    for (int r = 0; r < 4; ++r) wcv[r] += a * (float)hr[tid + r * 256];
  }
  float s1 = wcv[0] + wcv[1] + wcv[2] + wcv[3];
  float s2 = wcv[0] * wcv[0] + wcv[1] * wcv[1] + wcv[2] * wcv[2] + wcv[3] * wcv[3];
  s1 = wave_sum(s1);
  s2 = wave_sum(s2);
  if (lane == 0) { red_s[w] = s1; red_s[4 + w] = s2; }
  __syncthreads();
  const float S1 = red_s[0] + red_s[1] + red_s[2] + red_s[3];
  const float S2 = red_s[4] + red_s[5] + red_s[6] + red_s[7];
  const float mu = S1 * (1.f / H2);
  const float var = S2 * (1.f / H2) - mu * mu;
  const float rstd = rsqrtf(var + 1e-5f);
#pragma unroll
  for (int r = 0; r < 4; ++r) {
    const int e = tid + r * 256;
    const float y = (wcv[r] - mu) * rstd * g2[e] + b2[e];
    wc_f[(size_t)b * H2 + e] = y;
    gin_h[(size_t)b * H4 + H2 + e] = (_Float16)y;
  }
}

// ---------------- LN(nt_emb2[nt_id])
__global__ __launch_bounds__(256) void nt2_kernel(
    const float* __restrict__ nt_emb2, const int* __restrict__ nt_id,
    const float* __restrict__ g1, const float* __restrict__ b1,
    float* __restrict__ nt2_f, _Float16* __restrict__ gin_h) {
  __shared__ float red_s[8];
  const int b = blockIdx.x;
  const int tid = threadIdx.x;
  const int lane = tid & 63;
  const int w = tid >> 6;
  const float* x = nt_emb2 + (size_t)nt_id[b] * H2;
  float v[4];
  float s1 = 0.f, s2 = 0.f;
#pragma unroll
  for (int r = 0; r < 4; ++r) {
    v[r] = x[tid + r * 256];
    s1 += v[r];
    s2 += v[r] * v[r];
  }
  s1 = wave_sum(s1);
  s2 = wave_sum(s2);
  if (lane == 0) { red_s[w] = s1; red_s[4 + w] = s2; }
  __syncthreads();
  const float S1 = red_s[0] + red_s[1] + red_s[2] + red_s[3];
  const float S2 = red_s[4] + red_s[5] + red_s[6] + red_s[7];
  const float mu = S1 * (1.f / H2);
  const float var = S2 * (1.f / H2) - mu * mu;
  const float rstd = rsqrtf(var + 1e-5f);
#pragma unroll
  for (int r = 0; r < 4; ++r) {
    const int e = tid + r * 256;
    const float y = (v[r] - mu) * rstd * g1[e] + b1[e];
    nt2_f[(size_t)b * H2 + e] = y;
    gin_h[(size_t)b * H4 + e] = (_Float16)y;
  }
}

extern "C" void kernel_launch(void* const* d_in, const int* in_sizes, int n_in,
                              void* d_out, int out_size, void* d_ws, size_t ws_size,
                              hipStream_t stream) {
  const float* children = (const float*)d_in[0];
  const int* lens = (const int*)d_in[1];
  const int* nt_id = (const int*)d_in[3];
  const float* stack_state = (const float*)d_in[4];
  const float* Wih_f = (const float*)d_in[5];
  const float* Whh_f = (const float*)d_in[6];
  const float* bih_f = (const float*)d_in[7];
  const float* bhh_f = (const float*)d_in[8];
  const float* Wih_b = (const float*)d_in[9];
  const float* Whh_b = (const float*)d_in[10];
  const float* bih_b = (const float*)d_in[11];
  const float* bhh_b = (const float*)d_in[12];
  const float* V = (const float*)d_in[13];
  const float* nt_emb = (const float*)d_in[14];
  const float* nt_emb2 = (const float*)d_in[15];
  const float* ln1_g = (const float*)d_in[16];
  const float* ln1_b = (const float*)d_in[17];
  const float* ln2_g = (const float*)d_in[18];
  const float* ln2_b = (const float*)d_in[19];
  const float* gate_W = (const float*)d_in[20];
  const float* gate_b = (const float*)d_in[21];
  const float* out_W = (const float*)d_in[22];
  const float* out_b = (const float*)d_in[23];

  float* out = (float*)d_out;
  float* attn_out = out + (size_t)B_ * H_;
  float* g_out = attn_out + (size_t)B_ * L_;

  char* wsp = (char*)d_ws;
  size_t off = 0;
  auto alloc = [&](size_t bytes) {
    char* p = wsp + off;
    off += (bytes + 255) & ~(size_t)255;
    return p;
  };
  _Float16* ch_h = (_Float16*)alloc((size_t)B_ * L_ * H_ * 2);
  _Float16* h_all = (_Float16*)alloc((size_t)B_ * L_ * H2 * 2);
  _Float16* Wcat = (_Float16*)alloc((size_t)2 * H4 * H2 * 2);
  float* biascat = (float*)alloc((size_t)2 * H4 * 4);
  _Float16* Vt = (_Float16*)alloc((size_t)H2 * H2 * 2);
  _Float16* gateWh = (_Float16*)alloc((size_t)H2 * H4 * 2);
  _Float16* outWh = (_Float16*)alloc((size_t)H_ * H2 * 2);
  _Float16* rhs_h = (_Float16*)alloc((size_t)B_ * H2 * 2);
  float* u_f = (float*)alloc((size_t)B_ * H2 * 4);
  _Float16* hstate = (_Float16*)alloc((size_t)2 * 2 * B_ * H_ * 2);  // [parity][dir][B][H]
  float* cstate = (float*)alloc((size_t)2 * B_ * H_ * 4);
  float* wc_f = (float*)alloc((size_t)B_ * H2 * 4);
  float* nt2_f = (float*)alloc((size_t)B_ * H2 * 4);
  _Float16* gin_h = (_Float16*)alloc((size_t)B_ * H4 * 2);
  _Float16* cmix_h = (_Float16*)alloc((size_t)B_ * H2 * 2);
  int* sort_offs = (int*)alloc(64 * 4);
  int* sort_cursor = (int*)alloc(64 * 4);
  int* perm = (int*)alloc((size_t)B_ * 4);
  int* lens_sorted = (int*)alloc((size_t)B_ * 4);

  if (off > ws_size) {
    marker_k<<<1, 64, 0, stream>>>(out);
    return;
  }

  // ---- prep
  cast_half_k<<<32768, 256, 0, stream>>>(children, ch_h, B_ * L_ * H_);
  cast_half_k<<<2048, 256, 0, stream>>>(gate_W, gateWh, H2 * H4);
  cast_half_k<<<512, 256, 0, stream>>>(out_W, outWh, H_ * H2);
  pack_wcat<<<8192, 256, 0, stream>>>(Wih_f, Whh_f, Wih_b, Whh_b, Wcat);
  prep_misc<<<8192, 256, 0, stream>>>(nt_emb, nt_id, stack_state, rhs_h,
                                      V, Vt, bih_f, bhh_f, bih_b, bhh_b, biascat);
  hipMemsetAsync(hstate, 0, (size_t)2 * 2 * B_ * H_ * 2, stream);
  hipMemsetAsync(cstate, 0, (size_t)2 * B_ * H_ * 4, stream);
  sort1_k<<<1, 256, 0, stream>>>(lens, sort_offs, sort_cursor);
  sort2_k<<<8, 256, 0, stream>>>(lens, sort_offs, sort_cursor, perm, lens_sorted);
  nt2_kernel<<<2048, 256, 0, stream>>>(nt_emb2, nt_id, ln1_g, ln1_b, nt2_f, gin_h);

  // ---- u = rhs @ V
  gemm_bt<0><<<dim3(8, 16, 1), 256, 0, stream>>>(rhs_h, H2, Vt, H2, u_f, H2, H2,
                                                 nullptr, nullptr, nullptr, nullptr);

  // ---- bidirectional LSTM, 32 per-step launches (R8 pipeline)
  for (int t = 0; t < 32; ++t) {
    gemm_lstm<<<512, 256, 0, stream>>>(
        Wcat, biascat, ch_h, hstate, cstate, h_all, perm, lens_sorted, t);
  }

  // ---- attention + LN2
  attn_kernel<<<2048, 256, 0, stream>>>(h_all, u_f, lens, ln2_g, ln2_b, attn_out, wc_f, gin_h);

  // ---- gate MLP (fused sigmoid+mix epilogue)
  gemm_bt<1><<<dim3(8, 16, 1), 256, 0, stream>>>(gin_h, H4, gateWh, H4, g_out, H2, H4,
                                                 gate_b, nt2_f, wc_f, cmix_h);

  // ---- output projection (fused bias+ReLU epilogue)
  gemm_bt<2><<<dim3(4, 16, 1), 256, 0, stream>>>(cmix_h, H2, outWh, H2, out, H_, H2,
                                                 out_b, nullptr, nullptr, nullptr);
}